// Round 7
// baseline (2758.202 us; speedup 1.0000x reference)
//
#include <hip/hip_runtime.h>
#include <cstdint>
#include <cstddef>

#define U4    512   // 4*U
#define UNITS 128
#define BATCH 256
#define TSEQ  512
#define FEAT  64

typedef short short8 __attribute__((ext_vector_type(8)));
typedef float f32x4  __attribute__((ext_vector_type(4)));

// ---------------- fast activations (fp32, ~1e-7 rel err) ----------------
__device__ __forceinline__ float sigm(float x) {
    float e = __expf(-x);
    return __fdividef(1.0f, 1.0f + e);
}
__device__ __forceinline__ float tanh_fast(float x) {
    float e = __expf(2.0f * x);
    return 1.0f - __fdividef(2.0f, e + 1.0f);
}

// ---------------- bf16 split helpers (RNE) ----------------
__device__ __forceinline__ unsigned short f2bf(float f) {
    unsigned u = __float_as_uint(f);
    unsigned r = u + 0x7FFFu + ((u >> 16) & 1u);
    return (unsigned short)(r >> 16);
}
__device__ __forceinline__ float bf2f(unsigned short h) {
    return __uint_as_float(((unsigned)h) << 16);
}

// ---------------- projection GEMM (unchanged from R1) ----------------
__global__ __launch_bounds__(256, 4)
void proj_gemm(const float* __restrict__ in, const float* __restrict__ W,
               const float* __restrict__ bias, float* __restrict__ out,
               int K, int sB, int sT, int t0, int tcShift)
{
    const int tid = threadIdx.x;
    const int tx = tid & 31;
    const int ty = tid >> 5;
    const int m0 = blockIdx.x * 64;
    const int n0 = blockIdx.y * 128;
    const int TcMask = (1 << tcShift) - 1;

    __shared__ float As[32][68];
    __shared__ float Bs[32][128];

    float4 acc[8];
    #pragma unroll
    for (int i = 0; i < 8; ++i) acc[i] = make_float4(0.f, 0.f, 0.f, 0.f);

    for (int k0 = 0; k0 < K; k0 += 32) {
        #pragma unroll
        for (int i = 0; i < 8; ++i) {
            int l = i * 256 + tid;
            int row = l >> 5, kk = l & 31;
            int rg = m0 + row;
            int b = rg >> tcShift, tc = rg & TcMask;
            As[kk][row] = in[(size_t)b * sB + (size_t)(t0 + tc) * sT + k0 + kk];
        }
        #pragma unroll
        for (int i = 0; i < 4; ++i) {
            int l = i * 256 + tid;
            int kk = l >> 5, jq = l & 31;
            float4 w4 = *(const float4*)(W + (size_t)(k0 + kk) * U4 + n0 + jq * 4);
            *(float4*)(&Bs[kk][jq * 4]) = w4;
        }
        __syncthreads();
        #pragma unroll
        for (int kk = 0; kk < 32; ++kk) {
            float4 b4 = *(const float4*)(&Bs[kk][tx * 4]);
            float4 a0 = *(const float4*)(&As[kk][ty * 8]);
            float4 a1 = *(const float4*)(&As[kk][ty * 8 + 4]);
            float a[8] = {a0.x, a0.y, a0.z, a0.w, a1.x, a1.y, a1.z, a1.w};
            #pragma unroll
            for (int i = 0; i < 8; ++i) {
                acc[i].x = __builtin_fmaf(a[i], b4.x, acc[i].x);
                acc[i].y = __builtin_fmaf(a[i], b4.y, acc[i].y);
                acc[i].z = __builtin_fmaf(a[i], b4.z, acc[i].z);
                acc[i].w = __builtin_fmaf(a[i], b4.w, acc[i].w);
            }
        }
        __syncthreads();
    }

    float4 bb = *(const float4*)(bias + n0 + tx * 4);
    #pragma unroll
    for (int i = 0; i < 8; ++i) {
        int rg = m0 + ty * 8 + i;
        float4 v = acc[i];
        v.x += bb.x; v.y += bb.y; v.z += bb.z; v.w += bb.w;
        *(float4*)(out + (size_t)rg * U4 + n0 + tx * 4) = v;
    }
}

// ---------------- R -> bf16 hi/lo MFMA B-fragments ----------------
// B-layout for mfma_f32_16x16x32_bf16: lane holds B[k=quad*8+j][n=lane&15],
// 8 bf16/lane. Output: Rf[layer][nt(32)][kt(4)][pass(2)][lane(64)][8 shorts].
// pass 0 = bf16_hi(R), pass 1 = bf16 of (R - hi).
__global__ __launch_bounds__(256)
void r_frag(const float* __restrict__ R0, const float* __restrict__ R1,
            const float* __restrict__ R2, unsigned short* __restrict__ out)
{
    int gid = blockIdx.x * 256 + threadIdx.x;    // 3 * 16384
    int l    = gid >> 14;
    int nt   = (gid >> 9) & 31;
    int kt   = (gid >> 7) & 3;
    int pass = (gid >> 6) & 1;
    int lane = gid & 63;
    const float* R = (l == 0) ? R0 : (l == 1) ? R1 : R2;
    int n  = nt * 16 + (lane & 15);
    int k0 = kt * 32 + (lane >> 4) * 8;
    short8 v;
    #pragma unroll
    for (int j = 0; j < 8; ++j) {
        float x = R[(size_t)(k0 + j) * U4 + n];
        unsigned short hi = f2bf(x);
        unsigned short s = pass ? f2bf(x - bf2f(hi)) : hi;
        v[j] = (short)s;
    }
    *(short8*)(out + (size_t)gid * 8) = v;
}

// ---------------- LSTM recurrence via MFMA ----------------
// 1 block per sequence (all 256 CUs), 512 threads = 8 waves. Wave w owns
// gate-columns [w*64, w*64+64) = 4 N-tiles. The 128x512 matvec runs on the
// MFMA pipe: A rows 0/1 = h_hi/h_lo (bf16 split, 2^-17 rel err); pass1
// B=R_hi gives h_hi*R_hi (row0) + h_lo*R_hi (row1); pass2 B=R_lo gives
// h_hi*R_lo (row0). z = C1[0]+C1[1]+C2[0], all in lanes 0-15. B-frags
// (128 regs/lane) live in AGPRs where MFMA reads them NATIVELY — no
// v_accvgpr_read per MAC (R1-R6's 2-3 VALU/MAC tax, the whole bottleneck).
// ONE barrier/step: a_buf double-buffered; h_lds single buffer is safe
// because every wave redundantly writes the FULL h (identical values) and
// reads only its own writes (barrier orders cross-step write-after-read).
__global__ __launch_bounds__(512, 2)
void lstm_rec(const float* __restrict__ xw, const unsigned short* __restrict__ Rf,
              float* __restrict__ h_state, float* __restrict__ c_state,
              float* __restrict__ h_out, int Tc, int init)
{
    const int tid  = threadIdx.x;
    const int b    = blockIdx.x;
    const int lane = tid & 63;
    const int w    = tid >> 6;
    const int m    = lane & 15;
    const int quad = lane >> 4;

    __shared__ __align__(16) unsigned short h_lds[256]; // [0:128) hi, [128:256) lo
    __shared__ float a_buf[2][U4];

    // B fragments: bfrag[nt][kt][pass], loaded coalesced (b128 per lane)
    short8 bfrag[4][4][2];
    #pragma unroll
    for (int nt = 0; nt < 4; ++nt)
        #pragma unroll
        for (int kt = 0; kt < 4; ++kt)
            #pragma unroll
            for (int p = 0; p < 2; ++p)
                bfrag[nt][kt][p] = *(const short8*)(
                    Rf + ((size_t)(((w * 4 + nt) * 4 + kt) * 2 + p) * 64 + lane) * 8);

    // state: lane owns units (lane, lane+64); every wave keeps a redundant copy
    float c0 = 0.f, c1 = 0.f, hv0 = 0.f, hv1 = 0.f;
    if (!init) {
        hv0 = h_state[b * UNITS + lane];
        hv1 = h_state[b * UNITS + 64 + lane];
        c0  = c_state[b * UNITS + lane];
        c1  = c_state[b * UNITS + 64 + lane];
    }
    {   // every wave writes the full h split (redundant, identical values)
        unsigned short h0 = f2bf(hv0), h1 = f2bf(hv1);
        h_lds[lane]       = h0;  h_lds[128 + lane] = f2bf(hv0 - bf2f(h0));
        h_lds[64 + lane]  = h1;  h_lds[192 + lane] = f2bf(hv1 - bf2f(h1));
    }

    const float* xwB = xw + (size_t)b * Tc * U4;
    float xq[4] = {0.f, 0.f, 0.f, 0.f};
    if (lane < 16) {
        #pragma unroll
        for (int nt = 0; nt < 4; ++nt) xq[nt] = xwB[w * 64 + nt * 16 + m];
    }

    // accumulators live across the loop; only components 0,1 (pass1) and 0
    // (pass2) are re-zeroed per step (other rows never read; bounded growth)
    f32x4 ac1[4], ac2[4];
    #pragma unroll
    for (int nt = 0; nt < 4; ++nt) {
        ac1[nt] = (f32x4){0.f, 0.f, 0.f, 0.f};
        ac2[nt] = (f32x4){0.f, 0.f, 0.f, 0.f};
    }

    const int rowoff = (m == 0) ? 0 : 128;   // row0 -> h_hi, others -> h_lo
    int p = 0;

    #pragma unroll 1
    for (int t = 0; t < Tc; ++t) {
        // A-fragments from LDS (this wave's own writes; compiler orders via lgkmcnt)
        short8 afr[4];
        #pragma unroll
        for (int kt = 0; kt < 4; ++kt)
            afr[kt] = *(const short8*)(&h_lds[rowoff + kt * 32 + quad * 8]);

        // prefetch next step's xw under the MFMA chain
        float xn[4] = {0.f, 0.f, 0.f, 0.f};
        int tn = (t + 1 < Tc) ? (t + 1) : t;
        if (lane < 16) {
            #pragma unroll
            for (int nt = 0; nt < 4; ++nt) xn[nt] = xwB[(size_t)tn * U4 + w * 64 + nt * 16 + m];
        }

        #pragma unroll
        for (int nt = 0; nt < 4; ++nt) { ac1[nt].x = 0.f; ac1[nt].y = 0.f; ac2[nt].x = 0.f; }

        #pragma unroll
        for (int nt = 0; nt < 4; ++nt)
            #pragma unroll
            for (int kt = 0; kt < 4; ++kt) {
                ac1[nt] = __builtin_amdgcn_mfma_f32_16x16x32_bf16(afr[kt], bfrag[nt][kt][0], ac1[nt], 0, 0, 0);
                ac2[nt] = __builtin_amdgcn_mfma_f32_16x16x32_bf16(afr[kt], bfrag[nt][kt][1], ac2[nt], 0, 0, 0);
            }

        // Z + activation (lanes 0-15 hold rows 0/1 in regs 0/1); gate class
        // is wave-uniform: waves 0-3 sigm(i,f), 4-5 tanh(g), 6-7 sigm(o)
        if (lane < 16) {
            #pragma unroll
            for (int nt = 0; nt < 4; ++nt) {
                float z = ac1[nt].x + ac1[nt].y + ac2[nt].x + xq[nt];
                float a = (w == 4 || w == 5) ? tanh_fast(z) : sigm(z);
                a_buf[p][w * 64 + nt * 16 + m] = a;
            }
        }
        __syncthreads();   // a_buf[p] complete

        // phase B: every wave redundantly updates h/c for units (lane, lane+64)
        float iv0 = a_buf[p][lane];
        float fv0 = a_buf[p][lane + 128];
        float gv0 = a_buf[p][lane + 256];
        float ov0 = a_buf[p][lane + 384];
        float iv1 = a_buf[p][lane + 64];
        float fv1 = a_buf[p][lane + 192];
        float gv1 = a_buf[p][lane + 320];
        float ov1 = a_buf[p][lane + 448];

        c0 = __builtin_fmaf(fv0, c0, iv0 * gv0);
        c1 = __builtin_fmaf(fv1, c1, iv1 * gv1);
        hv0 = ov0 * tanh_fast(c0);
        hv1 = ov1 * tanh_fast(c1);

        unsigned short h0 = f2bf(hv0), h1 = f2bf(hv1);
        h_lds[lane]       = h0;  h_lds[128 + lane] = f2bf(hv0 - bf2f(h0));
        h_lds[64 + lane]  = h1;  h_lds[192 + lane] = f2bf(hv1 - bf2f(h1));

        if (h_out && w == 0) {
            h_out[((size_t)b * Tc + t) * UNITS + lane]      = hv0;
            h_out[((size_t)b * Tc + t) * UNITS + 64 + lane] = hv1;
        }

        xq[0] = xn[0]; xq[1] = xn[1]; xq[2] = xn[2]; xq[3] = xn[3];
        p ^= 1;
    }

    if (w == 0) {
        h_state[b * UNITS + lane]      = hv0;
        h_state[b * UNITS + 64 + lane] = hv1;
        c_state[b * UNITS + lane]      = c0;
        c_state[b * UNITS + 64 + lane] = c1;
    }
}

// ---------------- dense head ----------------
__global__ __launch_bounds__(256)
void dense_head(const float* __restrict__ h2, const float* __restrict__ Wd,
                const float* __restrict__ bd, float* __restrict__ out)
{
    int b = threadIdx.x;
    float acc[6];
    #pragma unroll
    for (int o = 0; o < 6; ++o) acc[o] = bd[o];
    #pragma unroll 4
    for (int k = 0; k < UNITS; ++k) {
        float hv = h2[b * UNITS + k];
        #pragma unroll
        for (int o = 0; o < 6; ++o)
            acc[o] = __builtin_fmaf(hv, Wd[k * 6 + o], acc[o]);
    }
    #pragma unroll
    for (int o = 0; o < 6; ++o) out[b * 6 + o] = acc[o];
}

extern "C" void kernel_launch(void* const* d_in, const int* in_sizes, int n_in,
                              void* d_out, int out_size, void* d_ws, size_t ws_size,
                              hipStream_t stream)
{
    (void)in_sizes; (void)n_in; (void)out_size;
    const float* x  = (const float*)d_in[0];
    const float* Ws[3] = {(const float*)d_in[1], (const float*)d_in[4], (const float*)d_in[7]};
    const float* Rs[3] = {(const float*)d_in[2], (const float*)d_in[5], (const float*)d_in[8]};
    const float* bs[3] = {(const float*)d_in[3], (const float*)d_in[6], (const float*)d_in[9]};
    const float* Wd = (const float*)d_in[10];
    const float* bd = (const float*)d_in[11];
    float* out = (float*)d_out;

    int tcShift = 7;
    while (tcShift > 2) {
        size_t need = ((size_t)1 << tcShift) * 655360u + 786432u + 786432u;
        if (need <= ws_size) break;
        --tcShift;
    }
    const int Tc = 1 << tcShift;

    float* xw = (float*)d_ws;                                // [B][Tc][512]
    float* hc = xw + (size_t)BATCH * Tc * U4;                // [B][Tc][128]
    float* hs = hc + (size_t)BATCH * Tc * UNITS;             // 3 x [B][128]
    float* cs = hs + 3 * BATCH * UNITS;                      // 3 x [B][128]
    unsigned short* Rf = (unsigned short*)(cs + 3 * BATCH * UNITS); // 3 x 128K shorts

    // precompute bf16 hi/lo MFMA B-fragments of R0..R2 (once per launch)
    r_frag<<<192, 256, 0, stream>>>(Rs[0], Rs[1], Rs[2], Rf);

    const int nChunks = TSEQ / Tc;
    for (int ch = 0; ch < nChunks; ++ch) {
        const int t0 = ch * Tc;
        for (int layer = 0; layer < 3; ++layer) {
            const float* in = (layer == 0) ? x : hc;
            const int K  = (layer == 0) ? FEAT : UNITS;
            const int sB = (layer == 0) ? TSEQ * FEAT : Tc * UNITS;
            const int sT = K;
            const int pt0 = (layer == 0) ? t0 : 0;

            dim3 grid(BATCH * Tc / 64, 4);
            proj_gemm<<<grid, 256, 0, stream>>>(in, Ws[layer], bs[layer], xw,
                                                K, sB, sT, pt0, tcShift);

            float* hOut = (layer < 2) ? hc : nullptr;
            lstm_rec<<<BATCH, 512, 0, stream>>>(xw, Rf + (size_t)layer * 131072,
                                                hs + layer * BATCH * UNITS,
                                                cs + layer * BATCH * UNITS,
                                                hOut, Tc, (ch == 0) ? 1 : 0);
        }
    }
    dense_head<<<1, 256, 0, stream>>>(hs + 2 * BATCH * UNITS, Wd, bd, out);
}

// Round 8
// 2153.761 us; speedup vs baseline: 1.2806x; 1.2806x over previous
//
#include <hip/hip_runtime.h>
#include <cstdint>
#include <cstddef>

#define U4    512   // 4*U
#define UNITS 128
#define BATCH 256
#define TSEQ  512
#define FEAT  64

typedef short short8 __attribute__((ext_vector_type(8)));
typedef float f32x4  __attribute__((ext_vector_type(4)));

// ---------------- fast activations (fp32, ~1e-7 rel err) ----------------
__device__ __forceinline__ float sigm(float x) {
    float e = __expf(-x);
    return __fdividef(1.0f, 1.0f + e);
}
__device__ __forceinline__ float tanh_fast(float x) {
    float e = __expf(2.0f * x);
    return 1.0f - __fdividef(2.0f, e + 1.0f);
}

// ---------------- bf16 split helpers (RNE) ----------------
__device__ __forceinline__ unsigned short f2bf(float f) {
    unsigned u = __float_as_uint(f);
    unsigned r = u + 0x7FFFu + ((u >> 16) & 1u);
    return (unsigned short)(r >> 16);
}
__device__ __forceinline__ float bf2f(unsigned short h) {
    return __uint_as_float(((unsigned)h) << 16);
}

// ---------------- projection GEMM (unchanged from R1) ----------------
__global__ __launch_bounds__(256, 4)
void proj_gemm(const float* __restrict__ in, const float* __restrict__ W,
               const float* __restrict__ bias, float* __restrict__ out,
               int K, int sB, int sT, int t0, int tcShift)
{
    const int tid = threadIdx.x;
    const int tx = tid & 31;
    const int ty = tid >> 5;
    const int m0 = blockIdx.x * 64;
    const int n0 = blockIdx.y * 128;
    const int TcMask = (1 << tcShift) - 1;

    __shared__ float As[32][68];
    __shared__ float Bs[32][128];

    float4 acc[8];
    #pragma unroll
    for (int i = 0; i < 8; ++i) acc[i] = make_float4(0.f, 0.f, 0.f, 0.f);

    for (int k0 = 0; k0 < K; k0 += 32) {
        #pragma unroll
        for (int i = 0; i < 8; ++i) {
            int l = i * 256 + tid;
            int row = l >> 5, kk = l & 31;
            int rg = m0 + row;
            int b = rg >> tcShift, tc = rg & TcMask;
            As[kk][row] = in[(size_t)b * sB + (size_t)(t0 + tc) * sT + k0 + kk];
        }
        #pragma unroll
        for (int i = 0; i < 4; ++i) {
            int l = i * 256 + tid;
            int kk = l >> 5, jq = l & 31;
            float4 w4 = *(const float4*)(W + (size_t)(k0 + kk) * U4 + n0 + jq * 4);
            *(float4*)(&Bs[kk][jq * 4]) = w4;
        }
        __syncthreads();
        #pragma unroll
        for (int kk = 0; kk < 32; ++kk) {
            float4 b4 = *(const float4*)(&Bs[kk][tx * 4]);
            float4 a0 = *(const float4*)(&As[kk][ty * 8]);
            float4 a1 = *(const float4*)(&As[kk][ty * 8 + 4]);
            float a[8] = {a0.x, a0.y, a0.z, a0.w, a1.x, a1.y, a1.z, a1.w};
            #pragma unroll
            for (int i = 0; i < 8; ++i) {
                acc[i].x = __builtin_fmaf(a[i], b4.x, acc[i].x);
                acc[i].y = __builtin_fmaf(a[i], b4.y, acc[i].y);
                acc[i].z = __builtin_fmaf(a[i], b4.z, acc[i].z);
                acc[i].w = __builtin_fmaf(a[i], b4.w, acc[i].w);
            }
        }
        __syncthreads();
    }

    float4 bb = *(const float4*)(bias + n0 + tx * 4);
    #pragma unroll
    for (int i = 0; i < 8; ++i) {
        int rg = m0 + ty * 8 + i;
        float4 v = acc[i];
        v.x += bb.x; v.y += bb.y; v.z += bb.z; v.w += bb.w;
        *(float4*)(out + (size_t)rg * U4 + n0 + tx * 4) = v;
    }
}

// ---------------- R -> bf16 hi/lo MFMA B-fragments (unchanged, validated R7) --
// B-layout for mfma_f32_16x16x32_bf16: lane holds B[k=quad*8+j][n=lane&15],
// 8 bf16/lane. Output: Rf[layer][nt_g(32)][kt(4)][pass(2)][lane(64)][8 shorts].
__global__ __launch_bounds__(256)
void r_frag(const float* __restrict__ R0, const float* __restrict__ R1,
            const float* __restrict__ R2, unsigned short* __restrict__ out)
{
    int gid = blockIdx.x * 256 + threadIdx.x;    // 3 * 16384
    int l    = gid >> 14;
    int nt   = (gid >> 9) & 31;
    int kt   = (gid >> 7) & 3;
    int pass = (gid >> 6) & 1;
    int lane = gid & 63;
    const float* R = (l == 0) ? R0 : (l == 1) ? R1 : R2;
    int n  = nt * 16 + (lane & 15);
    int k0 = kt * 32 + (lane >> 4) * 8;
    short8 v;
    #pragma unroll
    for (int j = 0; j < 8; ++j) {
        float x = R[(size_t)(k0 + j) * U4 + n];
        unsigned short hi = f2bf(x);
        unsigned short s = pass ? f2bf(x - bf2f(hi)) : hi;
        v[j] = (short)s;
    }
    *(short8*)(out + (size_t)gid * 8) = v;
}

// ---------------- LSTM recurrence via MFMA (v2) ----------------
// 1 block/seq, 512 threads = 8 waves; wave w owns gates [w*64, w*64+64).
// A-tile rows INTERLEAVED: row 2r = h_hi, row 2r+1 = h_lo (8 replicas).
// => lane (quad,m): A-frag = h_{m&1?lo:hi}[kt*32+quad*8 .. +8] (b128,
// 2-way-bank = free), and C regs 0/1 = (hi-row, lo-row) for col m in ALL
// lanes -> combine+act on all 64 lanes (R7 had it on lanes<16 only).
// ONE accumulator per N-tile: C init = xq (folds the xw add, kills per-step
// zeroing), 8 chained MFMAs (4kt x R_hi then 4kt x R_lo);
// z = C.x + C.y - xq  (= xw + h_hi@(Rhi+Rlo) + h_lo@(Rhi+Rlo): lo*lo now
// included -> better accuracy than R7). Lane keeps tile nt==quad -> gate
// index w*64+lane -> stride-1 a_buf write.
// One barrier/step (a_buf double-buffered); h_hi/h_lo single-buffered is
// safe: every wave writes the full split redundantly (identical values) and
// reads only its own writes; cross-step WAR is ordered by the barrier.
__global__ __launch_bounds__(512, 2)
void lstm_rec(const float* __restrict__ xw, const unsigned short* __restrict__ Rf,
              float* __restrict__ h_state, float* __restrict__ c_state,
              float* __restrict__ h_out, int Tc, int init)
{
    const int tid  = threadIdx.x;
    const int b    = blockIdx.x;
    const int lane = tid & 63;
    const int w    = tid >> 6;
    const int m    = lane & 15;
    const int quad = lane >> 4;

    __shared__ __align__(16) unsigned short h_hi[UNITS];
    __shared__ __align__(16) unsigned short h_lo[UNITS];
    __shared__ float a_buf[2][U4];

    // B fragments: bh/bl[nt][kt] (128 regs -> AGPRs; MFMA reads natively)
    short8 bh[4][4], bl[4][4];
    #pragma unroll
    for (int nt = 0; nt < 4; ++nt)
        #pragma unroll
        for (int kt = 0; kt < 4; ++kt) {
            size_t base = ((size_t)(((w * 4 + nt) * 4 + kt) * 2) * 64 + lane) * 8;
            bh[nt][kt] = *(const short8*)(Rf + base);
            bl[nt][kt] = *(const short8*)(Rf + base + 512);   // pass=1: +64*8
        }

    // state: lane owns units (lane, lane+64); every wave keeps a redundant copy
    float c0 = 0.f, c1 = 0.f, hv0 = 0.f, hv1 = 0.f;
    if (!init) {
        hv0 = h_state[b * UNITS + lane];
        hv1 = h_state[b * UNITS + 64 + lane];
        c0  = c_state[b * UNITS + lane];
        c1  = c_state[b * UNITS + 64 + lane];
    }
    {
        unsigned short u0 = f2bf(hv0), u1 = f2bf(hv1);
        h_hi[lane]      = u0;  h_lo[lane]      = f2bf(hv0 - bf2f(u0));
        h_hi[64 + lane] = u1;  h_lo[64 + lane] = f2bf(hv1 - bf2f(u1));
    }
    __syncthreads();

    // per-lane hi/lo selector for the A fragment (computed once)
    const unsigned short* hb = (m & 1) ? h_lo : h_hi;

    // xw: every lane loads its column's 4 N-tile values (16 distinct/wave, L2)
    const float* xwB = xw + (size_t)b * Tc * U4 + w * 64 + m;
    float xq0 = xwB[0], xq1 = xwB[16], xq2 = xwB[32], xq3 = xwB[48];

    const bool is_g = (w == 4 || w == 5);
    int p = 0;

    #pragma unroll 1
    for (int t = 0; t < Tc; ++t) {
        // A fragments (own-wave h writes; b128, 2-way bank = free)
        short8 a0 = *(const short8*)(hb + 0 * 32 + quad * 8);
        short8 a1 = *(const short8*)(hb + 1 * 32 + quad * 8);
        short8 a2 = *(const short8*)(hb + 2 * 32 + quad * 8);
        short8 a3 = *(const short8*)(hb + 3 * 32 + quad * 8);

        // prefetch next step's xw under the MFMA chain
        int tn = (t + 1 < Tc) ? (t + 1) : t;
        const float* xwN = xwB + (size_t)tn * U4;
        float y0 = xwN[0], y1 = xwN[16], y2 = xwN[32], y3 = xwN[48];

        // one accumulator per N-tile, C init = xq (all 4 regs)
        f32x4 A0 = {xq0, xq0, xq0, xq0};
        f32x4 A1 = {xq1, xq1, xq1, xq1};
        f32x4 A2 = {xq2, xq2, xq2, xq2};
        f32x4 A3 = {xq3, xq3, xq3, xq3};

        A0 = __builtin_amdgcn_mfma_f32_16x16x32_bf16(a0, bh[0][0], A0, 0, 0, 0);
        A1 = __builtin_amdgcn_mfma_f32_16x16x32_bf16(a0, bh[1][0], A1, 0, 0, 0);
        A2 = __builtin_amdgcn_mfma_f32_16x16x32_bf16(a0, bh[2][0], A2, 0, 0, 0);
        A3 = __builtin_amdgcn_mfma_f32_16x16x32_bf16(a0, bh[3][0], A3, 0, 0, 0);
        A0 = __builtin_amdgcn_mfma_f32_16x16x32_bf16(a1, bh[0][1], A0, 0, 0, 0);
        A1 = __builtin_amdgcn_mfma_f32_16x16x32_bf16(a1, bh[1][1], A1, 0, 0, 0);
        A2 = __builtin_amdgcn_mfma_f32_16x16x32_bf16(a1, bh[2][1], A2, 0, 0, 0);
        A3 = __builtin_amdgcn_mfma_f32_16x16x32_bf16(a1, bh[3][1], A3, 0, 0, 0);
        A0 = __builtin_amdgcn_mfma_f32_16x16x32_bf16(a2, bh[0][2], A0, 0, 0, 0);
        A1 = __builtin_amdgcn_mfma_f32_16x16x32_bf16(a2, bh[1][2], A1, 0, 0, 0);
        A2 = __builtin_amdgcn_mfma_f32_16x16x32_bf16(a2, bh[2][2], A2, 0, 0, 0);
        A3 = __builtin_amdgcn_mfma_f32_16x16x32_bf16(a2, bh[3][2], A3, 0, 0, 0);
        A0 = __builtin_amdgcn_mfma_f32_16x16x32_bf16(a3, bh[0][3], A0, 0, 0, 0);
        A1 = __builtin_amdgcn_mfma_f32_16x16x32_bf16(a3, bh[1][3], A1, 0, 0, 0);
        A2 = __builtin_amdgcn_mfma_f32_16x16x32_bf16(a3, bh[2][3], A2, 0, 0, 0);
        A3 = __builtin_amdgcn_mfma_f32_16x16x32_bf16(a3, bh[3][3], A3, 0, 0, 0);
        A0 = __builtin_amdgcn_mfma_f32_16x16x32_bf16(a0, bl[0][0], A0, 0, 0, 0);
        A1 = __builtin_amdgcn_mfma_f32_16x16x32_bf16(a0, bl[1][0], A1, 0, 0, 0);
        A2 = __builtin_amdgcn_mfma_f32_16x16x32_bf16(a0, bl[2][0], A2, 0, 0, 0);
        A3 = __builtin_amdgcn_mfma_f32_16x16x32_bf16(a0, bl[3][0], A3, 0, 0, 0);
        A0 = __builtin_amdgcn_mfma_f32_16x16x32_bf16(a1, bl[0][1], A0, 0, 0, 0);
        A1 = __builtin_amdgcn_mfma_f32_16x16x32_bf16(a1, bl[1][1], A1, 0, 0, 0);
        A2 = __builtin_amdgcn_mfma_f32_16x16x32_bf16(a1, bl[2][1], A2, 0, 0, 0);
        A3 = __builtin_amdgcn_mfma_f32_16x16x32_bf16(a1, bl[3][1], A3, 0, 0, 0);
        A0 = __builtin_amdgcn_mfma_f32_16x16x32_bf16(a2, bl[0][2], A0, 0, 0, 0);
        A1 = __builtin_amdgcn_mfma_f32_16x16x32_bf16(a2, bl[1][2], A1, 0, 0, 0);
        A2 = __builtin_amdgcn_mfma_f32_16x16x32_bf16(a2, bl[2][2], A2, 0, 0, 0);
        A3 = __builtin_amdgcn_mfma_f32_16x16x32_bf16(a2, bl[3][2], A3, 0, 0, 0);
        A0 = __builtin_amdgcn_mfma_f32_16x16x32_bf16(a3, bl[0][3], A0, 0, 0, 0);
        A1 = __builtin_amdgcn_mfma_f32_16x16x32_bf16(a3, bl[1][3], A1, 0, 0, 0);
        A2 = __builtin_amdgcn_mfma_f32_16x16x32_bf16(a3, bl[2][3], A2, 0, 0, 0);
        A3 = __builtin_amdgcn_mfma_f32_16x16x32_bf16(a3, bl[3][3], A3, 0, 0, 0);

        // lane keeps tile nt == quad: z = C.x + C.y - xq  (rows 4q, 4q+1)
        float r0 = (quad == 0) ? A0.x : (quad == 1) ? A1.x : (quad == 2) ? A2.x : A3.x;
        float r1 = (quad == 0) ? A0.y : (quad == 1) ? A1.y : (quad == 2) ? A2.y : A3.y;
        float xz = (quad == 0) ? xq0  : (quad == 1) ? xq1  : (quad == 2) ? xq2  : xq3;
        float z = (r0 + r1) - xz;
        float a = is_g ? tanh_fast(z) : sigm(z);
        a_buf[p][w * 64 + lane] = a;            // stride-1: gate n = w*64+lane

        __syncthreads();   // a_buf[p] complete

        // phase B: every wave redundantly updates h/c for units (lane, lane+64)
        float iv0 = a_buf[p][lane];
        float fv0 = a_buf[p][lane + 128];
        float gv0 = a_buf[p][lane + 256];
        float ov0 = a_buf[p][lane + 384];
        float iv1 = a_buf[p][lane + 64];
        float fv1 = a_buf[p][lane + 192];
        float gv1 = a_buf[p][lane + 320];
        float ov1 = a_buf[p][lane + 448];

        c0 = __builtin_fmaf(fv0, c0, iv0 * gv0);
        c1 = __builtin_fmaf(fv1, c1, iv1 * gv1);
        hv0 = ov0 * tanh_fast(c0);
        hv1 = ov1 * tanh_fast(c1);

        unsigned short u0 = f2bf(hv0), u1 = f2bf(hv1);
        h_hi[lane]      = u0;  h_lo[lane]      = f2bf(hv0 - bf2f(u0));
        h_hi[64 + lane] = u1;  h_lo[64 + lane] = f2bf(hv1 - bf2f(u1));

        if (h_out && w == 0) {
            h_out[((size_t)b * Tc + t) * UNITS + lane]      = hv0;
            h_out[((size_t)b * Tc + t) * UNITS + 64 + lane] = hv1;
        }

        xq0 = y0; xq1 = y1; xq2 = y2; xq3 = y3;
        p ^= 1;
    }

    if (w == 0) {
        h_state[b * UNITS + lane]      = hv0;
        h_state[b * UNITS + 64 + lane] = hv1;
        c_state[b * UNITS + lane]      = c0;
        c_state[b * UNITS + 64 + lane] = c1;
    }
}

// ---------------- dense head ----------------
__global__ __launch_bounds__(256)
void dense_head(const float* __restrict__ h2, const float* __restrict__ Wd,
                const float* __restrict__ bd, float* __restrict__ out)
{
    int b = threadIdx.x;
    float acc[6];
    #pragma unroll
    for (int o = 0; o < 6; ++o) acc[o] = bd[o];
    #pragma unroll 4
    for (int k = 0; k < UNITS; ++k) {
        float hv = h2[b * UNITS + k];
        #pragma unroll
        for (int o = 0; o < 6; ++o)
            acc[o] = __builtin_fmaf(hv, Wd[k * 6 + o], acc[o]);
    }
    #pragma unroll
    for (int o = 0; o < 6; ++o) out[b * 6 + o] = acc[o];
}

extern "C" void kernel_launch(void* const* d_in, const int* in_sizes, int n_in,
                              void* d_out, int out_size, void* d_ws, size_t ws_size,
                              hipStream_t stream)
{
    (void)in_sizes; (void)n_in; (void)out_size;
    const float* x  = (const float*)d_in[0];
    const float* Ws[3] = {(const float*)d_in[1], (const float*)d_in[4], (const float*)d_in[7]};
    const float* Rs[3] = {(const float*)d_in[2], (const float*)d_in[5], (const float*)d_in[8]};
    const float* bs[3] = {(const float*)d_in[3], (const float*)d_in[6], (const float*)d_in[9]};
    const float* Wd = (const float*)d_in[10];
    const float* bd = (const float*)d_in[11];
    float* out = (float*)d_out;

    int tcShift = 7;
    while (tcShift > 2) {
        size_t need = ((size_t)1 << tcShift) * 655360u + 786432u + 786432u;
        if (need <= ws_size) break;
        --tcShift;
    }
    const int Tc = 1 << tcShift;

    float* xw = (float*)d_ws;                                // [B][Tc][512]
    float* hc = xw + (size_t)BATCH * Tc * U4;                // [B][Tc][128]
    float* hs = hc + (size_t)BATCH * Tc * UNITS;             // 3 x [B][128]
    float* cs = hs + 3 * BATCH * UNITS;                      // 3 x [B][128]
    unsigned short* Rf = (unsigned short*)(cs + 3 * BATCH * UNITS); // 3 x 128K shorts

    // precompute bf16 hi/lo MFMA B-fragments of R0..R2 (once per launch)
    r_frag<<<192, 256, 0, stream>>>(Rs[0], Rs[1], Rs[2], Rf);

    const int nChunks = TSEQ / Tc;
    for (int ch = 0; ch < nChunks; ++ch) {
        const int t0 = ch * Tc;
        for (int layer = 0; layer < 3; ++layer) {
            const float* in = (layer == 0) ? x : hc;
            const int K  = (layer == 0) ? FEAT : UNITS;
            const int sB = (layer == 0) ? TSEQ * FEAT : Tc * UNITS;
            const int sT = K;
            const int pt0 = (layer == 0) ? t0 : 0;

            dim3 grid(BATCH * Tc / 64, 4);
            proj_gemm<<<grid, 256, 0, stream>>>(in, Ws[layer], bs[layer], xw,
                                                K, sB, sT, pt0, tcShift);

            float* hOut = (layer < 2) ? hc : nullptr;
            lstm_rec<<<BATCH, 512, 0, stream>>>(xw, Rf + (size_t)layer * 131072,
                                                hs + layer * BATCH * UNITS,
                                                cs + layer * BATCH * UNITS,
                                                hOut, Tc, (ch == 0) ? 1 : 0);
        }
    }
    dense_head<<<1, 256, 0, stream>>>(hs + 2 * BATCH * UNITS, Wd, bd, out);
}

// Round 9
// 2106.042 us; speedup vs baseline: 1.3097x; 1.0227x over previous
//
#include <hip/hip_runtime.h>
#include <cstdint>
#include <cstddef>

#define U4    512   // 4*U
#define UNITS 128
#define BATCH 256
#define TSEQ  512
#define FEAT  64

typedef short short8 __attribute__((ext_vector_type(8)));
typedef float f32x4  __attribute__((ext_vector_type(4)));

// ---------------- fast activations (fp32, ~1e-7 rel err) ----------------
__device__ __forceinline__ float sigm(float x) {
    float e = __expf(-x);
    return __fdividef(1.0f, 1.0f + e);
}
__device__ __forceinline__ float tanh_fast(float x) {
    float e = __expf(2.0f * x);
    return 1.0f - __fdividef(2.0f, e + 1.0f);
}

// ---------------- bf16 split helpers (RNE) ----------------
__device__ __forceinline__ unsigned short f2bf(float f) {
    unsigned u = __float_as_uint(f);
    unsigned r = u + 0x7FFFu + ((u >> 16) & 1u);
    return (unsigned short)(r >> 16);
}
__device__ __forceinline__ float bf2f(unsigned short h) {
    return __uint_as_float(((unsigned)h) << 16);
}

// ---------------- projection GEMM (unchanged from R1) ----------------
__global__ __launch_bounds__(256, 4)
void proj_gemm(const float* __restrict__ in, const float* __restrict__ W,
               const float* __restrict__ bias, float* __restrict__ out,
               int K, int sB, int sT, int t0, int tcShift)
{
    const int tid = threadIdx.x;
    const int tx = tid & 31;
    const int ty = tid >> 5;
    const int m0 = blockIdx.x * 64;
    const int n0 = blockIdx.y * 128;
    const int TcMask = (1 << tcShift) - 1;

    __shared__ float As[32][68];
    __shared__ float Bs[32][128];

    float4 acc[8];
    #pragma unroll
    for (int i = 0; i < 8; ++i) acc[i] = make_float4(0.f, 0.f, 0.f, 0.f);

    for (int k0 = 0; k0 < K; k0 += 32) {
        #pragma unroll
        for (int i = 0; i < 8; ++i) {
            int l = i * 256 + tid;
            int row = l >> 5, kk = l & 31;
            int rg = m0 + row;
            int b = rg >> tcShift, tc = rg & TcMask;
            As[kk][row] = in[(size_t)b * sB + (size_t)(t0 + tc) * sT + k0 + kk];
        }
        #pragma unroll
        for (int i = 0; i < 4; ++i) {
            int l = i * 256 + tid;
            int kk = l >> 5, jq = l & 31;
            float4 w4 = *(const float4*)(W + (size_t)(k0 + kk) * U4 + n0 + jq * 4);
            *(float4*)(&Bs[kk][jq * 4]) = w4;
        }
        __syncthreads();
        #pragma unroll
        for (int kk = 0; kk < 32; ++kk) {
            float4 b4 = *(const float4*)(&Bs[kk][tx * 4]);
            float4 a0 = *(const float4*)(&As[kk][ty * 8]);
            float4 a1 = *(const float4*)(&As[kk][ty * 8 + 4]);
            float a[8] = {a0.x, a0.y, a0.z, a0.w, a1.x, a1.y, a1.z, a1.w};
            #pragma unroll
            for (int i = 0; i < 8; ++i) {
                acc[i].x = __builtin_fmaf(a[i], b4.x, acc[i].x);
                acc[i].y = __builtin_fmaf(a[i], b4.y, acc[i].y);
                acc[i].z = __builtin_fmaf(a[i], b4.z, acc[i].z);
                acc[i].w = __builtin_fmaf(a[i], b4.w, acc[i].w);
            }
        }
        __syncthreads();
    }

    float4 bb = *(const float4*)(bias + n0 + tx * 4);
    #pragma unroll
    for (int i = 0; i < 8; ++i) {
        int rg = m0 + ty * 8 + i;
        float4 v = acc[i];
        v.x += bb.x; v.y += bb.y; v.z += bb.z; v.w += bb.w;
        *(float4*)(out + (size_t)rg * U4 + n0 + tx * 4) = v;
    }
}

// ---------------- R -> bf16 hi/lo MFMA B-fragments (validated R7/R8) --------
// B-layout for mfma_f32_16x16x32_bf16: lane holds B[k=quad*8+j][n=lane&15].
// Rf[layer][nt(32)][kt(4)][pass(2)][lane(64)][8 shorts].
__global__ __launch_bounds__(256)
void r_frag(const float* __restrict__ R0, const float* __restrict__ R1,
            const float* __restrict__ R2, unsigned short* __restrict__ out)
{
    int gid = blockIdx.x * 256 + threadIdx.x;    // 3 * 16384
    int l    = gid >> 14;
    int nt   = (gid >> 9) & 31;
    int kt   = (gid >> 7) & 3;
    int pass = (gid >> 6) & 1;
    int lane = gid & 63;
    const float* R = (l == 0) ? R0 : (l == 1) ? R1 : R2;
    int n  = nt * 16 + (lane & 15);
    int k0 = kt * 32 + (lane >> 4) * 8;
    short8 v;
    #pragma unroll
    for (int j = 0; j < 8; ++j) {
        float x = R[(size_t)(k0 + j) * U4 + n];
        unsigned short hi = f2bf(x);
        unsigned short s = pass ? f2bf(x - bf2f(hi)) : hi;
        v[j] = (short)s;
    }
    *(short8*)(out + (size_t)gid * 8) = v;
}

// ---------------- LSTM recurrence via MFMA (v3: K-split waves) ----------
// 1 block/seq (256 blocks), 1024 threads = 16 waves, 4 waves/SIMD.
// Wave task = (ng = w>>1 : cols [ng*64,+64)) x (kh = w&1 : K [kh*64,+64)).
// Per wave: 16 MFMAs, B-frags = 16 short8 = 64 regs  -> fits the 128-reg/wave
// cap at 4 waves/SIMD (R8's 128-reg B set never got arch residency).
// A-tile: row 0 = h_hi, row 1 = h_lo, rows 2-15 ZERO -> A-frag load is
// exec-masked to lanes m<2 (others {0}): kills ~700cyc/step of LDS reads
// that were 15/16 zeros in R8.
// K-split partials abuf[gate][kh]; phase B (tid<128, non-redundant): b64
// partial-pair reads, z=p0+p1, activations, c/h update, bf16-split h write.
// 2 barriers/step (producer->abuf->consumer, h->next A-frag). Accuracy path
// identical to R8 (validated 1.5e-5).
__global__ __launch_bounds__(1024)
void lstm_rec(const float* __restrict__ xw, const unsigned short* __restrict__ Rf,
              float* __restrict__ h_state, float* __restrict__ c_state,
              float* __restrict__ h_out, int Tc, int init)
{
    const int tid  = threadIdx.x;
    const int b    = blockIdx.x;
    const int lane = tid & 63;
    const int w    = tid >> 6;       // 0..15
    const int ng   = w >> 1;         // 0..7  cols [ng*64, ng*64+64)
    const int kh   = w & 1;          // 0..1  K    [kh*64, kh*64+64)
    const int m    = lane & 15;
    const int quad = lane >> 4;

    __shared__ __align__(16) unsigned short htab[2][136];  // row0=h_hi row1=h_lo (full K=128)
    __shared__ __align__(8)  float abuf[U4][2];            // [gate][khalf] partials

    // B fragments: [nt j][kt i][pass] = 16 short8 = 64 regs
    short8 bf[4][2][2];
    #pragma unroll
    for (int j = 0; j < 4; ++j)
        #pragma unroll
        for (int i = 0; i < 2; ++i)
            #pragma unroll
            for (int pp = 0; pp < 2; ++pp) {
                int nt = ng * 4 + j, kt = kh * 2 + i;
                bf[j][i][pp] = *(const short8*)(
                    Rf + ((size_t)((nt * 4 + kt) * 2 + pp) * 64 + lane) * 8);
            }

    const int u = tid & 127;
    float c = 0.f;
    if (tid < 128) {
        float hv = 0.f;
        if (!init) {
            hv = h_state[b * UNITS + u];
            c  = c_state[b * UNITS + u];
        }
        unsigned short hi = f2bf(hv);
        htab[0][u] = hi;
        htab[1][u] = f2bf(hv - bf2f(hi));
    }
    __syncthreads();

    const float* xwB = xw + (size_t)b * Tc * U4;
    const int col0 = ng * 64 + m;
    float xa0 = xwB[col0], xa1 = xwB[col0 + 16], xa2 = xwB[col0 + 32], xa3 = xwB[col0 + 48];

    #pragma unroll 1
    for (int t = 0; t < Tc; ++t) {
        // ---- phase A: partial z on MFMA pipe ----
        // A-frags: rows >=2 are zero -> masked load, lanes m<2 only
        short8 af0 = {0,0,0,0,0,0,0,0};
        short8 af1 = {0,0,0,0,0,0,0,0};
        if (m < 2) {
            af0 = *(const short8*)(&htab[m][kh * 64 + quad * 8]);
            af1 = *(const short8*)(&htab[m][kh * 64 + 32 + quad * 8]);
        }

        // prefetch next step's xw under the MFMA chain
        int tn = (t + 1 < Tc) ? (t + 1) : t;
        const float* xwN = xwB + (size_t)tn * U4;
        float y0 = xwN[col0], y1 = xwN[col0 + 16], y2 = xwN[col0 + 32], y3 = xwN[col0 + 48];

        // C init: kh==0 folds xw (z = C.x + C.y - xa adds it exactly once)
        float i0 = kh ? 0.f : xa0, i1 = kh ? 0.f : xa1;
        float i2 = kh ? 0.f : xa2, i3 = kh ? 0.f : xa3;
        f32x4 C0 = {i0, i0, i0, i0};
        f32x4 C1 = {i1, i1, i1, i1};
        f32x4 C2 = {i2, i2, i2, i2};
        f32x4 C3 = {i3, i3, i3, i3};

        C0 = __builtin_amdgcn_mfma_f32_16x16x32_bf16(af0, bf[0][0][0], C0, 0, 0, 0);
        C1 = __builtin_amdgcn_mfma_f32_16x16x32_bf16(af0, bf[1][0][0], C1, 0, 0, 0);
        C2 = __builtin_amdgcn_mfma_f32_16x16x32_bf16(af0, bf[2][0][0], C2, 0, 0, 0);
        C3 = __builtin_amdgcn_mfma_f32_16x16x32_bf16(af0, bf[3][0][0], C3, 0, 0, 0);
        C0 = __builtin_amdgcn_mfma_f32_16x16x32_bf16(af1, bf[0][1][0], C0, 0, 0, 0);
        C1 = __builtin_amdgcn_mfma_f32_16x16x32_bf16(af1, bf[1][1][0], C1, 0, 0, 0);
        C2 = __builtin_amdgcn_mfma_f32_16x16x32_bf16(af1, bf[2][1][0], C2, 0, 0, 0);
        C3 = __builtin_amdgcn_mfma_f32_16x16x32_bf16(af1, bf[3][1][0], C3, 0, 0, 0);
        C0 = __builtin_amdgcn_mfma_f32_16x16x32_bf16(af0, bf[0][0][1], C0, 0, 0, 0);
        C1 = __builtin_amdgcn_mfma_f32_16x16x32_bf16(af0, bf[1][0][1], C1, 0, 0, 0);
        C2 = __builtin_amdgcn_mfma_f32_16x16x32_bf16(af0, bf[2][0][1], C2, 0, 0, 0);
        C3 = __builtin_amdgcn_mfma_f32_16x16x32_bf16(af0, bf[3][0][1], C3, 0, 0, 0);
        C0 = __builtin_amdgcn_mfma_f32_16x16x32_bf16(af1, bf[0][1][1], C0, 0, 0, 0);
        C1 = __builtin_amdgcn_mfma_f32_16x16x32_bf16(af1, bf[1][1][1], C1, 0, 0, 0);
        C2 = __builtin_amdgcn_mfma_f32_16x16x32_bf16(af1, bf[2][1][1], C2, 0, 0, 0);
        C3 = __builtin_amdgcn_mfma_f32_16x16x32_bf16(af1, bf[3][1][1], C3, 0, 0, 0);

        if (quad == 0) {   // rows 0,1 live in quad-0 lanes, regs .x/.y
            abuf[col0     ][kh] = C0.x + C0.y - i0;
            abuf[col0 + 16][kh] = C1.x + C1.y - i1;
            abuf[col0 + 32][kh] = C2.x + C2.y - i2;
            abuf[col0 + 48][kh] = C3.x + C3.y - i3;
        }
        __syncthreads();   // barrier 1: abuf complete

        // ---- phase B: combine + activate + c/h update (non-redundant) ----
        if (tid < 128) {
            const float2* ab = (const float2*)abuf;
            float2 pi = ab[u];
            float2 pf = ab[u + 128];
            float2 pg = ab[u + 256];
            float2 po = ab[u + 384];
            float iv = sigm(pi.x + pi.y);
            float fv = sigm(pf.x + pf.y);
            float gv = tanh_fast(pg.x + pg.y);
            float ov = sigm(po.x + po.y);
            c = __builtin_fmaf(fv, c, iv * gv);
            float hv = ov * tanh_fast(c);
            unsigned short hi = f2bf(hv);
            htab[0][u] = hi;
            htab[1][u] = f2bf(hv - bf2f(hi));
            if (h_out) h_out[((size_t)b * Tc + t) * UNITS + u] = hv;
        }
        __syncthreads();   // barrier 2: htab ready for next A-frag

        xa0 = y0; xa1 = y1; xa2 = y2; xa3 = y3;
    }

    if (tid < 128) {
        c_state[b * UNITS + u] = c;
        h_state[b * UNITS + u] = bf2f(htab[0][u]) + bf2f(htab[1][u]);
    }
}

// ---------------- dense head ----------------
__global__ __launch_bounds__(256)
void dense_head(const float* __restrict__ h2, const float* __restrict__ Wd,
                const float* __restrict__ bd, float* __restrict__ out)
{
    int b = threadIdx.x;
    float acc[6];
    #pragma unroll
    for (int o = 0; o < 6; ++o) acc[o] = bd[o];
    #pragma unroll 4
    for (int k = 0; k < UNITS; ++k) {
        float hv = h2[b * UNITS + k];
        #pragma unroll
        for (int o = 0; o < 6; ++o)
            acc[o] = __builtin_fmaf(hv, Wd[k * 6 + o], acc[o]);
    }
    #pragma unroll
    for (int o = 0; o < 6; ++o) out[b * 6 + o] = acc[o];
}

extern "C" void kernel_launch(void* const* d_in, const int* in_sizes, int n_in,
                              void* d_out, int out_size, void* d_ws, size_t ws_size,
                              hipStream_t stream)
{
    (void)in_sizes; (void)n_in; (void)out_size;
    const float* x  = (const float*)d_in[0];
    const float* Ws[3] = {(const float*)d_in[1], (const float*)d_in[4], (const float*)d_in[7]};
    const float* Rs[3] = {(const float*)d_in[2], (const float*)d_in[5], (const float*)d_in[8]};
    const float* bs[3] = {(const float*)d_in[3], (const float*)d_in[6], (const float*)d_in[9]};
    const float* Wd = (const float*)d_in[10];
    const float* bd = (const float*)d_in[11];
    float* out = (float*)d_out;

    int tcShift = 7;
    while (tcShift > 2) {
        size_t need = ((size_t)1 << tcShift) * 655360u + 786432u + 786432u;
        if (need <= ws_size) break;
        --tcShift;
    }
    const int Tc = 1 << tcShift;

    float* xw = (float*)d_ws;                                // [B][Tc][512]
    float* hc = xw + (size_t)BATCH * Tc * U4;                // [B][Tc][128]
    float* hs = hc + (size_t)BATCH * Tc * UNITS;             // 3 x [B][128]
    float* cs = hs + 3 * BATCH * UNITS;                      // 3 x [B][128]
    unsigned short* Rf = (unsigned short*)(cs + 3 * BATCH * UNITS); // 3 x 128K shorts

    // precompute bf16 hi/lo MFMA B-fragments of R0..R2 (once per launch)
    r_frag<<<192, 256, 0, stream>>>(Rs[0], Rs[1], Rs[2], Rf);

    const int nChunks = TSEQ / Tc;
    for (int ch = 0; ch < nChunks; ++ch) {
        const int t0 = ch * Tc;
        for (int layer = 0; layer < 3; ++layer) {
            const float* in = (layer == 0) ? x : hc;
            const int K  = (layer == 0) ? FEAT : UNITS;
            const int sB = (layer == 0) ? TSEQ * FEAT : Tc * UNITS;
            const int sT = K;
            const int pt0 = (layer == 0) ? t0 : 0;

            dim3 grid(BATCH * Tc / 64, 4);
            proj_gemm<<<grid, 256, 0, stream>>>(in, Ws[layer], bs[layer], xw,
                                                K, sB, sT, pt0, tcShift);

            float* hOut = (layer < 2) ? hc : nullptr;
            lstm_rec<<<BATCH, 1024, 0, stream>>>(xw, Rf + (size_t)layer * 131072,
                                                 hs + layer * BATCH * UNITS,
                                                 cs + layer * BATCH * UNITS,
                                                 hOut, Tc, (ch == 0) ? 1 : 0);
        }
    }
    dense_head<<<1, 256, 0, stream>>>(hs + 2 * BATCH * UNITS, Wd, bd, out);
}